// Round 1
// baseline (390.338 us; speedup 1.0000x reference)
//
#include <hip/hip_runtime.h>
#include <hip/hip_bf16.h>
#include <math.h>

// Problem constants: B=4, T=4096, C=1024, H=16, D=64, BLOCK=128
//   M = B*T = 16384 rows
//   GEMM1: [16384,1024] @ [1024,3072] -> qkv
//   attn : 2048 blocks of (128x64) q,k,v, causal-within-block softmax
//   GEMM2: [16384,1024] @ [1024,1024] + bias -> out (fp32)

typedef __bf16 bf16_t;
typedef __bf16 bf16x8 __attribute__((ext_vector_type(8)));
typedef float  f32x4  __attribute__((ext_vector_type(4)));

typedef const __attribute__((address_space(1))) void* gptr_t;
typedef __attribute__((address_space(3))) void* lptr_t;

// ---------------------------------------------------------------- cvt: f32 -> bf16
__global__ __launch_bounds__(256) void cvt_f32_bf16(const float* __restrict__ in,
                                                    bf16_t* __restrict__ out, size_t n) {
    size_t stride = (size_t)gridDim.x * blockDim.x * 4;
    for (size_t i = ((size_t)blockIdx.x * blockDim.x + threadIdx.x) * 4; i < n; i += stride) {
        float4 v = *(const float4*)(in + i);
        bf16_t t[4];
        t[0] = (bf16_t)v.x; t[1] = (bf16_t)v.y; t[2] = (bf16_t)v.z; t[3] = (bf16_t)v.w;
        *(uint2*)(out + i) = *(uint2*)t;
    }
}

// ------------------------------------------------- transpose+cvt: W[K][N] -> Wt[N][K] bf16
__global__ __launch_bounds__(256) void transpose_cvt(const float* __restrict__ in,
                                                     bf16_t* __restrict__ out, int K, int N) {
    int idx = blockIdx.x * 256 + threadIdx.x;   // linear over out [N][K]
    if (idx < N * K) {
        int nn = idx / K;
        int kk = idx - nn * K;
        out[idx] = (bf16_t)in[(size_t)kk * N + nn];
    }
}

// ---------------------------------------------------------------- GEMM (B-transposed)
// C[M][N] = A[M][K] * Bt[N][K]^T   (all bf16 in, fp32 accum)
// 128x128 tile, BK=32, 256 threads = 4 waves in 2x2, 64x64 per wave (4x4 MFMA frags).
template <bool BF16_OUT, bool BIAS>
__global__ __launch_bounds__(256) void gemm_bt(const bf16_t* __restrict__ A,
                                               const bf16_t* __restrict__ Bt,
                                               void* __restrict__ Cout,
                                               const float* __restrict__ bias,
                                               int M, int N, int K) {
    __shared__ bf16_t As[128 * 32];
    __shared__ bf16_t Bs[128 * 32];

    const int bn = blockIdx.x, bm = blockIdx.y;
    const int tid = threadIdx.x;
    const int lane = tid & 63, wave = tid >> 6;
    const int wm = wave >> 1, wn = wave & 1;
    const int quad = lane >> 4, l16 = lane & 15;

    const bf16_t* Ab = A  + (size_t)bm * 128 * K;
    const bf16_t* Bb = Bt + (size_t)bn * 128 * K;

    f32x4 acc[4][4];
    for (int i = 0; i < 4; i++)
        for (int j = 0; j < 4; j++)
            acc[i][j] = (f32x4){0.f, 0.f, 0.f, 0.f};

    // staging geometry: tile is 128 rows x 64 bytes; one wave-instr = 64 lanes x 16B = 16 rows.
    const int srow = lane >> 2;          // 0..15 row within 16-row slab
    const int scb  = (lane & 3) * 16;    // byte offset within 64B row chunk

    for (int k0 = 0; k0 < K; k0 += 32) {
        #pragma unroll
        for (int i = 0; i < 2; i++) {
            const int s = wave * 2 + i;                 // slab 0..7 (16 rows each)
            const int row = s * 16 + srow;
            __builtin_amdgcn_global_load_lds(
                (gptr_t)((const char*)(Ab + (size_t)row * K + k0) + scb),
                (lptr_t)&As[s * 512], 16, 0, 0);
            __builtin_amdgcn_global_load_lds(
                (gptr_t)((const char*)(Bb + (size_t)row * K + k0) + scb),
                (lptr_t)&Bs[s * 512], 16, 0, 0);
        }
        __syncthreads();

        bf16x8 af[4], bf[4];
        #pragma unroll
        for (int mr = 0; mr < 4; mr++)
            af[mr] = *(const bf16x8*)&As[(wm * 64 + mr * 16 + l16) * 32 + quad * 8];
        #pragma unroll
        for (int nr = 0; nr < 4; nr++)
            bf[nr] = *(const bf16x8*)&Bs[(wn * 64 + nr * 16 + l16) * 32 + quad * 8];
        #pragma unroll
        for (int mr = 0; mr < 4; mr++)
            #pragma unroll
            for (int nr = 0; nr < 4; nr++)
                acc[mr][nr] = __builtin_amdgcn_mfma_f32_16x16x32_bf16(af[mr], bf[nr], acc[mr][nr], 0, 0, 0);
        __syncthreads();
    }

    // epilogue: C/D layout col=lane&15, row=quad*4+reg
    #pragma unroll
    for (int mr = 0; mr < 4; mr++) {
        #pragma unroll
        for (int nr = 0; nr < 4; nr++) {
            const int gcol = bn * 128 + wn * 64 + nr * 16 + l16;
            #pragma unroll
            for (int reg = 0; reg < 4; reg++) {
                const int grow = bm * 128 + wm * 64 + mr * 16 + quad * 4 + reg;
                float v = acc[mr][nr][reg];
                if (BIAS) v += bias[gcol];
                if (BF16_OUT)
                    ((bf16_t*)Cout)[(size_t)grow * N + gcol] = (bf16_t)v;
                else
                    ((float*)Cout)[(size_t)grow * N + gcol] = v;
            }
        }
    }
}

// ---------------------------------------------------------------- block-local attention
// One workgroup per (b, blk, h). q,k,v: 128x64 bf16. S=QK^T/8, tril mask, softmax
// (max-sub, exp, /(sum+1e-6)), O=PV. qkv layout [16384][3072], out [16384][1024] bf16.
__global__ __launch_bounds__(256) void attn_kernel(const bf16_t* __restrict__ qkv,
                                                   bf16_t* __restrict__ attn_out) {
    // LDS: qs/ks/vs [128][72] bf16 (pad 72 breaks bank conflicts); P overlays qs+ks.
    __shared__ __align__(16) char smem[3 * 128 * 72 * 2];
    bf16_t* qs = (bf16_t*)smem;                      // [128][72]
    bf16_t* ks = (bf16_t*)(smem + 128 * 72 * 2);     // [128][72]
    bf16_t* vs = (bf16_t*)(smem + 2 * 128 * 72 * 2); // [128][72]
    bf16_t* ps = (bf16_t*)smem;                      // [128][136] overlays qs+ks (34816B <= 36864B)

    const int tid = threadIdx.x;
    const int lane = tid & 63, wave = tid >> 6;
    const int quad = lane >> 4, l16 = lane & 15;

    const int bid = blockIdx.x;
    const int h = bid & 15;
    const int blk = (bid >> 4) & 31;
    const int b = bid >> 9;
    const int row0 = (b * 32 + blk) * 128;   // row base in [16384]
    const int LDQ = 3072;

    // ---- stage q,k,v (each row: 64 bf16 = 8 chunks of 16B)
    for (int t = tid; t < 128 * 8; t += 256) {
        const int r = t >> 3;
        const int c = (t & 7) * 8;           // element offset
        const bf16_t* src = qkv + (size_t)(row0 + r) * LDQ + h * 64;
        *(uint4*)&qs[r * 72 + c] = *(const uint4*)(src + c);
        *(uint4*)&ks[r * 72 + c] = *(const uint4*)(src + 1024 + c);
        *(uint4*)&vs[r * 72 + c] = *(const uint4*)(src + 2048 + c);
    }
    __syncthreads();

    // ---- S = q k^T / 8 : wave handles rows [wave*32, wave*32+32) x 128 cols
    f32x4 sfrag[2][8];
    for (int mr = 0; mr < 2; mr++)
        for (int nc = 0; nc < 8; nc++)
            sfrag[mr][nc] = (f32x4){0.f, 0.f, 0.f, 0.f};

    #pragma unroll
    for (int ksl = 0; ksl < 2; ksl++) {     // K=64 in two slices of 32
        bf16x8 aq[2], bk[8];
        #pragma unroll
        for (int mr = 0; mr < 2; mr++)
            aq[mr] = *(const bf16x8*)&qs[(wave * 32 + mr * 16 + l16) * 72 + ksl * 32 + quad * 8];
        #pragma unroll
        for (int nc = 0; nc < 8; nc++)
            bk[nc] = *(const bf16x8*)&ks[(nc * 16 + l16) * 72 + ksl * 32 + quad * 8];
        #pragma unroll
        for (int mr = 0; mr < 2; mr++)
            #pragma unroll
            for (int nc = 0; nc < 8; nc++)
                sfrag[mr][nc] = __builtin_amdgcn_mfma_f32_16x16x32_bf16(aq[mr], bk[nc], sfrag[mr][nc], 0, 0, 0);
    }

    // ---- scale + causal mask (in C-layout: row=quad*4+reg, col=nc*16+l16)
    #pragma unroll
    for (int mr = 0; mr < 2; mr++) {
        #pragma unroll
        for (int nc = 0; nc < 8; nc++) {
            #pragma unroll
            for (int reg = 0; reg < 4; reg++) {
                const int row = wave * 32 + mr * 16 + quad * 4 + reg;
                const int col = nc * 16 + l16;
                float s = sfrag[mr][nc][reg] * 0.125f;
                if (col > row) s = -INFINITY;
                sfrag[mr][nc][reg] = s;
            }
        }
    }

    // ---- softmax per row (reduce over 16 lanes of the quad + 8 col frags)
    #pragma unroll
    for (int mr = 0; mr < 2; mr++) {
        #pragma unroll
        for (int reg = 0; reg < 4; reg++) {
            float m = -INFINITY;
            #pragma unroll
            for (int nc = 0; nc < 8; nc++) m = fmaxf(m, sfrag[mr][nc][reg]);
            #pragma unroll
            for (int off = 1; off < 16; off <<= 1) m = fmaxf(m, __shfl_xor(m, off));
            float sum = 0.f;
            #pragma unroll
            for (int nc = 0; nc < 8; nc++) {
                float e = __expf(sfrag[mr][nc][reg] - m);
                sfrag[mr][nc][reg] = e;
                sum += e;
            }
            #pragma unroll
            for (int off = 1; off < 16; off <<= 1) sum += __shfl_xor(sum, off);
            const float inv = 1.0f / (sum + 1e-6f);
            #pragma unroll
            for (int nc = 0; nc < 8; nc++) sfrag[mr][nc][reg] *= inv;
        }
    }

    __syncthreads();   // everyone done reading qs/ks before P overlays them

    // ---- write P (bf16) to LDS [128][136]
    #pragma unroll
    for (int mr = 0; mr < 2; mr++)
        #pragma unroll
        for (int nc = 0; nc < 8; nc++)
            #pragma unroll
            for (int reg = 0; reg < 4; reg++) {
                const int row = wave * 32 + mr * 16 + quad * 4 + reg;
                const int col = nc * 16 + l16;
                ps[row * 136 + col] = (bf16_t)sfrag[mr][nc][reg];
            }
    __syncthreads();

    // ---- O = P @ V : rows [wave*32, +32) x 64 cols, K=128 in 4 slices
    f32x4 oacc[2][4];
    for (int mr = 0; mr < 2; mr++)
        for (int nd = 0; nd < 4; nd++)
            oacc[mr][nd] = (f32x4){0.f, 0.f, 0.f, 0.f};

    #pragma unroll
    for (int ksl = 0; ksl < 4; ksl++) {
        bf16x8 ap[2];
        #pragma unroll
        for (int mr = 0; mr < 2; mr++)
            ap[mr] = *(const bf16x8*)&ps[(wave * 32 + mr * 16 + l16) * 136 + ksl * 32 + quad * 8];
        #pragma unroll
        for (int nd = 0; nd < 4; nd++) {
            bf16x8 bv;
            #pragma unroll
            for (int jj = 0; jj < 8; jj++)
                bv[jj] = vs[(ksl * 32 + quad * 8 + jj) * 72 + nd * 16 + l16];
            #pragma unroll
            for (int mr = 0; mr < 2; mr++)
                oacc[mr][nd] = __builtin_amdgcn_mfma_f32_16x16x32_bf16(ap[mr], bv, oacc[mr][nd], 0, 0, 0);
        }
    }

    // ---- store O bf16 into attn buffer [16384][1024]
    #pragma unroll
    for (int mr = 0; mr < 2; mr++)
        #pragma unroll
        for (int nd = 0; nd < 4; nd++)
            #pragma unroll
            for (int reg = 0; reg < 4; reg++) {
                const int row = row0 + wave * 32 + mr * 16 + quad * 4 + reg;
                const int col = h * 64 + nd * 16 + l16;
                attn_out[(size_t)row * 1024 + col] = (bf16_t)oacc[mr][nd][reg];
            }
}

// ---------------------------------------------------------------- launch
extern "C" void kernel_launch(void* const* d_in, const int* in_sizes, int n_in,
                              void* d_out, int out_size, void* d_ws, size_t ws_size,
                              hipStream_t stream) {
    const float* x     = (const float*)d_in[0];   // [4,4096,1024]
    const float* Wqkv  = (const float*)d_in[1];   // [1024,3072]
    const float* Wproj = (const float*)d_in[2];   // [1024,1024]
    const float* bproj = (const float*)d_in[3];   // [1024]

    const int M = 16384, C = 1024, N1 = 3072;

    // workspace carve (bytes): all 16B aligned
    char* ws = (char*)d_ws;
    bf16_t* xb     = (bf16_t*)(ws);                                   // 32 MB
    bf16_t* wqkvT  = (bf16_t*)(ws + 33554432);                        //  6 MB  [3072][1024]
    bf16_t* wprojT = (bf16_t*)(ws + 39845888);                        //  2 MB  [1024][1024]
    bf16_t* qkvb   = (bf16_t*)(ws + 41943040);                        // 96 MB  [16384][3072]
    bf16_t* attnb  = (bf16_t*)(ws + 142606336);                       // 32 MB  [16384][1024]
    // total 168 MB

    cvt_f32_bf16<<<8192, 256, 0, stream>>>(x, xb, (size_t)M * C);
    transpose_cvt<<<(N1 * C) / 256, 256, 0, stream>>>(Wqkv, wqkvT, C, N1);
    transpose_cvt<<<(C * C) / 256, 256, 0, stream>>>(Wproj, wprojT, C, C);

    gemm_bt<true, false><<<dim3(N1 / 128, M / 128), 256, 0, stream>>>(
        xb, wqkvT, (void*)qkvb, nullptr, M, N1, C);

    attn_kernel<<<2048, 256, 0, stream>>>(qkvb, attnb);

    gemm_bt<false, true><<<dim3(C / 128, M / 128), 256, 0, stream>>>(
        attnb, wprojT, d_out, bproj, M, C, C);
}

// Round 2
// 350.700 us; speedup vs baseline: 1.1130x; 1.1130x over previous
//
#include <hip/hip_runtime.h>
#include <hip/hip_bf16.h>
#include <math.h>

// Problem constants: B=4, T=4096, C=1024, H=16, D=64, BLOCK=128
//   M = B*T = 16384 rows
//   GEMM1: [16384,1024] @ [1024,3072] -> qkv
//   attn : 2048 blocks of (128x64) q,k,v, causal-within-block softmax
//   GEMM2: [16384,1024] @ [1024,1024] + bias -> out (fp32)

typedef __bf16 bf16_t;
typedef __bf16 bf16x8 __attribute__((ext_vector_type(8)));
typedef float  f32x4  __attribute__((ext_vector_type(4)));

typedef const __attribute__((address_space(1))) void* gptr_t;
typedef __attribute__((address_space(3))) void* lptr_t;

// ---------------------------------------------------------------- cvt: f32 -> bf16
__global__ __launch_bounds__(256) void cvt_f32_bf16(const float* __restrict__ in,
                                                    bf16_t* __restrict__ out, size_t n) {
    size_t stride = (size_t)gridDim.x * blockDim.x * 4;
    for (size_t i = ((size_t)blockIdx.x * blockDim.x + threadIdx.x) * 4; i < n; i += stride) {
        float4 v = *(const float4*)(in + i);
        bf16_t t[4];
        t[0] = (bf16_t)v.x; t[1] = (bf16_t)v.y; t[2] = (bf16_t)v.z; t[3] = (bf16_t)v.w;
        *(uint2*)(out + i) = *(uint2*)t;
    }
}

// ------------------------------- transpose+cvt: W[K][N] fp32 -> Wt[N][K] bf16, LDS-tiled
__global__ __launch_bounds__(256) void transpose_cvt(const float* __restrict__ in,
                                                     bf16_t* __restrict__ out, int K, int N) {
    __shared__ float tile[32][33];
    const int tx = threadIdx.x & 31, ty = threadIdx.x >> 5;   // 32 x 8
    const int bx = blockIdx.x, by = blockIdx.y;               // N/32, K/32
    #pragma unroll
    for (int i = 0; i < 4; i++) {
        const int k = by * 32 + ty + i * 8;
        tile[ty + i * 8][tx] = in[(size_t)k * N + bx * 32 + tx];
    }
    __syncthreads();
    #pragma unroll
    for (int i = 0; i < 4; i++) {
        const int n = bx * 32 + ty + i * 8;
        out[(size_t)n * K + by * 32 + tx] = (bf16_t)tile[tx][ty + i * 8];
    }
}

// ---------------------------------------------------------------- GEMM (B-transposed)
// C[M][N] = A[M][K] * Bt[N][K]^T   (bf16 in, fp32 accum)
// 128x128 tile, BK=64 via twin 32-wide slabs (32 MFMA per barrier pair), 4 waves 2x2.
template <bool BF16_OUT, bool BIAS>
__global__ __launch_bounds__(256) void gemm_bt(const bf16_t* __restrict__ A,
                                               const bf16_t* __restrict__ Bt,
                                               void* __restrict__ Cout,
                                               const float* __restrict__ bias,
                                               int M, int N, int K) {
    __shared__ bf16_t As[2][128 * 32];
    __shared__ bf16_t Bs[2][128 * 32];

    const int bn = blockIdx.x, bm = blockIdx.y;
    const int tid = threadIdx.x;
    const int lane = tid & 63, wave = tid >> 6;
    const int wm = wave >> 1, wn = wave & 1;
    const int quad = lane >> 4, l16 = lane & 15;

    const bf16_t* Ab = A  + (size_t)bm * 128 * K;
    const bf16_t* Bb = Bt + (size_t)bn * 128 * K;

    f32x4 acc[4][4];
    for (int i = 0; i < 4; i++)
        for (int j = 0; j < 4; j++)
            acc[i][j] = (f32x4){0.f, 0.f, 0.f, 0.f};

    // staging geometry: slab = 16 rows x 32 bf16 (64B); one wave-instr = 64 lanes x 16B.
    const int srow = lane >> 2;          // 0..15 row within 16-row slab
    const int scb  = (lane & 3) * 16;    // byte offset within 64B row chunk

    for (int k0 = 0; k0 < K; k0 += 64) {
        #pragma unroll
        for (int half = 0; half < 2; half++) {
            #pragma unroll
            for (int i = 0; i < 2; i++) {
                const int s = wave * 2 + i;                 // slab 0..7 (16 rows each)
                const int row = s * 16 + srow;
                const int kk = k0 + half * 32;
                __builtin_amdgcn_global_load_lds(
                    (gptr_t)((const char*)(Ab + (size_t)row * K + kk) + scb),
                    (lptr_t)&As[half][s * 512], 16, 0, 0);
                __builtin_amdgcn_global_load_lds(
                    (gptr_t)((const char*)(Bb + (size_t)row * K + kk) + scb),
                    (lptr_t)&Bs[half][s * 512], 16, 0, 0);
            }
        }
        __syncthreads();

        #pragma unroll
        for (int half = 0; half < 2; half++) {
            bf16x8 af[4], bf[4];
            #pragma unroll
            for (int mr = 0; mr < 4; mr++)
                af[mr] = *(const bf16x8*)&As[half][(wm * 64 + mr * 16 + l16) * 32 + quad * 8];
            #pragma unroll
            for (int nr = 0; nr < 4; nr++)
                bf[nr] = *(const bf16x8*)&Bs[half][(wn * 64 + nr * 16 + l16) * 32 + quad * 8];
            #pragma unroll
            for (int mr = 0; mr < 4; mr++)
                #pragma unroll
                for (int nr = 0; nr < 4; nr++)
                    acc[mr][nr] = __builtin_amdgcn_mfma_f32_16x16x32_bf16(af[mr], bf[nr], acc[mr][nr], 0, 0, 0);
        }
        __syncthreads();
    }

    // epilogue: C/D layout col=lane&15, row=quad*4+reg
    #pragma unroll
    for (int mr = 0; mr < 4; mr++) {
        #pragma unroll
        for (int nr = 0; nr < 4; nr++) {
            const int gcol = bn * 128 + wn * 64 + nr * 16 + l16;
            #pragma unroll
            for (int reg = 0; reg < 4; reg++) {
                const int grow = bm * 128 + wm * 64 + mr * 16 + quad * 4 + reg;
                float v = acc[mr][nr][reg];
                if (BIAS) v += bias[gcol];
                if (BF16_OUT)
                    ((bf16_t*)Cout)[(size_t)grow * N + gcol] = (bf16_t)v;
                else
                    ((float*)Cout)[(size_t)grow * N + gcol] = v;
            }
        }
    }
}

// ---------------------------------------------------------------- block-local attention
// One workgroup per (b, blk, h). q,k: [128][72] LDS; v stored TRANSPOSED [64][136] so
// PV B-fragments are ds_read_b128. LDS total 54272 B -> 3 blocks/CU.
__global__ __launch_bounds__(256, 3) void attn_kernel(const bf16_t* __restrict__ qkv,
                                                      bf16_t* __restrict__ attn_out) {
    __shared__ __align__(16) char smem[54272];
    bf16_t* qs = (bf16_t*)smem;                   // [128][72]
    bf16_t* ks = (bf16_t*)(smem + 18432);         // [128][72]
    bf16_t* vT = (bf16_t*)(smem + 36864);         // [64][136]  vT[c][r] = v[r][c]
    bf16_t* ps = (bf16_t*)smem;                   // [128][136] overlays qs+ks (34816 <= 36864)

    const int tid = threadIdx.x;
    const int lane = tid & 63, wave = tid >> 6;
    const int quad = lane >> 4, l16 = lane & 15;

    const int bid = blockIdx.x;
    const int h = bid & 15;
    const int blk = (bid >> 4) & 31;
    const int b = bid >> 9;
    const int row0 = (b * 32 + blk) * 128;   // row base in [16384]
    const int LDQ = 3072;

    // ---- stage q,k (vector), v transposed (scalar scatter, one-time)
    for (int t = tid; t < 128 * 8; t += 256) {
        const int r = t >> 3;
        const int c = (t & 7) * 8;           // element offset
        const bf16_t* src = qkv + (size_t)(row0 + r) * LDQ + h * 64;
        *(uint4*)&qs[r * 72 + c] = *(const uint4*)(src + c);
        *(uint4*)&ks[r * 72 + c] = *(const uint4*)(src + 1024 + c);
        bf16x8 vv = *(const bf16x8*)(src + 2048 + c);
        #pragma unroll
        for (int j = 0; j < 8; j++)
            vT[(c + j) * 136 + r] = vv[j];
    }
    __syncthreads();

    // ---- S = q k^T / 8 : wave handles rows [wave*32, wave*32+32) x 128 cols
    f32x4 sfrag[2][8];
    for (int mr = 0; mr < 2; mr++)
        for (int nc = 0; nc < 8; nc++)
            sfrag[mr][nc] = (f32x4){0.f, 0.f, 0.f, 0.f};

    #pragma unroll
    for (int ksl = 0; ksl < 2; ksl++) {     // K=64 in two slices of 32
        bf16x8 aq[2], bk[8];
        #pragma unroll
        for (int mr = 0; mr < 2; mr++)
            aq[mr] = *(const bf16x8*)&qs[(wave * 32 + mr * 16 + l16) * 72 + ksl * 32 + quad * 8];
        #pragma unroll
        for (int nc = 0; nc < 8; nc++)
            bk[nc] = *(const bf16x8*)&ks[(nc * 16 + l16) * 72 + ksl * 32 + quad * 8];
        #pragma unroll
        for (int mr = 0; mr < 2; mr++)
            #pragma unroll
            for (int nc = 0; nc < 8; nc++)
                sfrag[mr][nc] = __builtin_amdgcn_mfma_f32_16x16x32_bf16(aq[mr], bk[nc], sfrag[mr][nc], 0, 0, 0);
    }

    // ---- scale + causal mask (C-layout: row=quad*4+reg, col=nc*16+l16)
    #pragma unroll
    for (int mr = 0; mr < 2; mr++) {
        #pragma unroll
        for (int nc = 0; nc < 8; nc++) {
            #pragma unroll
            for (int reg = 0; reg < 4; reg++) {
                const int row = wave * 32 + mr * 16 + quad * 4 + reg;
                const int col = nc * 16 + l16;
                float s = sfrag[mr][nc][reg] * 0.125f;
                if (col > row) s = -INFINITY;
                sfrag[mr][nc][reg] = s;
            }
        }
    }

    // ---- softmax per row (reduce across 16 lanes of the row-group + 8 col frags)
    #pragma unroll
    for (int mr = 0; mr < 2; mr++) {
        #pragma unroll
        for (int reg = 0; reg < 4; reg++) {
            float m = -INFINITY;
            #pragma unroll
            for (int nc = 0; nc < 8; nc++) m = fmaxf(m, sfrag[mr][nc][reg]);
            #pragma unroll
            for (int off = 1; off < 16; off <<= 1) m = fmaxf(m, __shfl_xor(m, off));
            float sum = 0.f;
            #pragma unroll
            for (int nc = 0; nc < 8; nc++) {
                float e = __expf(sfrag[mr][nc][reg] - m);
                sfrag[mr][nc][reg] = e;
                sum += e;
            }
            #pragma unroll
            for (int off = 1; off < 16; off <<= 1) sum += __shfl_xor(sum, off);
            const float inv = 1.0f / (sum + 1e-6f);
            #pragma unroll
            for (int nc = 0; nc < 8; nc++) sfrag[mr][nc][reg] *= inv;
        }
    }

    __syncthreads();   // all waves done reading qs/ks before P overlays them

    // ---- write P (bf16) to LDS [128][136]
    #pragma unroll
    for (int mr = 0; mr < 2; mr++)
        #pragma unroll
        for (int nc = 0; nc < 8; nc++)
            #pragma unroll
            for (int reg = 0; reg < 4; reg++) {
                const int row = wave * 32 + mr * 16 + quad * 4 + reg;
                const int col = nc * 16 + l16;
                ps[row * 136 + col] = (bf16_t)sfrag[mr][nc][reg];
            }
    __syncthreads();

    // ---- O = P @ V : rows [wave*32, +32) x 64 cols, K=128 in 4 slices; V from vT (b128)
    f32x4 oacc[2][4];
    for (int mr = 0; mr < 2; mr++)
        for (int nd = 0; nd < 4; nd++)
            oacc[mr][nd] = (f32x4){0.f, 0.f, 0.f, 0.f};

    #pragma unroll
    for (int ksl = 0; ksl < 4; ksl++) {
        bf16x8 ap[2];
        #pragma unroll
        for (int mr = 0; mr < 2; mr++)
            ap[mr] = *(const bf16x8*)&ps[(wave * 32 + mr * 16 + l16) * 136 + ksl * 32 + quad * 8];
        #pragma unroll
        for (int nd = 0; nd < 4; nd++) {
            bf16x8 bv = *(const bf16x8*)&vT[(nd * 16 + l16) * 136 + ksl * 32 + quad * 8];
            #pragma unroll
            for (int mr = 0; mr < 2; mr++)
                oacc[mr][nd] = __builtin_amdgcn_mfma_f32_16x16x32_bf16(ap[mr], bv, oacc[mr][nd], 0, 0, 0);
        }
    }

    // ---- store O bf16 into attn buffer [16384][1024]
    #pragma unroll
    for (int mr = 0; mr < 2; mr++)
        #pragma unroll
        for (int nd = 0; nd < 4; nd++)
            #pragma unroll
            for (int reg = 0; reg < 4; reg++) {
                const int row = row0 + wave * 32 + mr * 16 + quad * 4 + reg;
                const int col = h * 64 + nd * 16 + l16;
                attn_out[(size_t)row * 1024 + col] = (bf16_t)oacc[mr][nd][reg];
            }
}

// ---------------------------------------------------------------- launch
extern "C" void kernel_launch(void* const* d_in, const int* in_sizes, int n_in,
                              void* d_out, int out_size, void* d_ws, size_t ws_size,
                              hipStream_t stream) {
    const float* x     = (const float*)d_in[0];   // [4,4096,1024]
    const float* Wqkv  = (const float*)d_in[1];   // [1024,3072]
    const float* Wproj = (const float*)d_in[2];   // [1024,1024]
    const float* bproj = (const float*)d_in[3];   // [1024]

    const int M = 16384, C = 1024, N1 = 3072;

    // workspace carve (bytes): all 16B aligned
    char* ws = (char*)d_ws;
    bf16_t* xb     = (bf16_t*)(ws);                                   // 32 MB
    bf16_t* wqkvT  = (bf16_t*)(ws + 33554432);                        //  6 MB  [3072][1024]
    bf16_t* wprojT = (bf16_t*)(ws + 39845888);                        //  2 MB  [1024][1024]
    bf16_t* qkvb   = (bf16_t*)(ws + 41943040);                        // 96 MB  [16384][3072]
    bf16_t* attnb  = (bf16_t*)(ws + 142606336);                       // 32 MB  [16384][1024]
    // total 168 MB

    cvt_f32_bf16<<<8192, 256, 0, stream>>>(x, xb, (size_t)M * C);
    transpose_cvt<<<dim3(N1 / 32, C / 32), 256, 0, stream>>>(Wqkv, wqkvT, C, N1);
    transpose_cvt<<<dim3(C / 32, C / 32), 256, 0, stream>>>(Wproj, wprojT, C, C);

    gemm_bt<true, false><<<dim3(N1 / 128, M / 128), 256, 0, stream>>>(
        xb, wqkvT, (void*)qkvb, nullptr, M, N1, C);

    attn_kernel<<<2048, 256, 0, stream>>>(qkvb, attnb);

    gemm_bt<false, true><<<dim3(C / 128, M / 128), 256, 0, stream>>>(
        attnb, wprojT, d_out, bproj, M, C, C);
}